// Round 11
// baseline (82.322 us; speedup 1.0000x reference)
//
#include <hip/hip_runtime.h>
#include <math.h>

// Problem constants (from reference)
#define NUM_T   8      // NUM_NODE_TYPES
#define TIN     16     // 2 * NUM_NODE_TYPES
#define HID     64     // HIDDEN
#define OUTD    16     // D*D
#define LN_EPS  1e-5f

#define N_PACK_U32  12500   // ceil(100000 / 8) ; 12500 % 4 == 0
#define PACK_BLOCKS 49      // ceil(12500 / 256)

typedef float f32x4 __attribute__((ext_vector_type(4)));

// ---------------------------------------------------------------------------
// k0: pack node types to nibbles only (8 per u32). 49 blocks, ~1.5 us.
// The 64-entry table is now rebuilt inside every scatter block (overlapped
// with its nibble staging) to cut prep->scatter serialization.
// ws: [0,50KB) packed nibbles.
// ---------------------------------------------------------------------------
__global__ __launch_bounds__(256) void
pack_kernel(const int* __restrict__ ntypes, int n_nodes,
            unsigned int* __restrict__ packed)
{
    const int g = blockIdx.x * 256 + threadIdx.x;
    if (g < N_PACK_U32) {
        unsigned int w = 0;
        int n0 = g * 8;
        #pragma unroll
        for (int j = 0; j < 8; ++j) {
            int n = n0 + j;
            unsigned int ty = (n < n_nodes) ? (unsigned int)ntypes[n] : 0u;
            w |= (ty & 7u) << (j * 4);
        }
        packed[g] = w;
    }
}

// ---------------------------------------------------------------------------
// In-block table build: wave `wid` computes pairs wid*4..wid*4+3.
// Per pair: lane k=0..63 computes relu(hn @ W1 + b1)[k] with coalesced
// W1-column reads, then two 8-output passes (low VGPR) of a*W2[k] with a
// 6-step butterfly reduce; lanes 0/1 finish softmax rows and write LDS.
// ---------------------------------------------------------------------------
__device__ __forceinline__ void
build_table_inblock(int wid, int lane,
                    const float* __restrict__ ln_g,
                    const float* __restrict__ ln_b,
                    const float* __restrict__ W1,
                    const float* __restrict__ b1,
                    const float* __restrict__ W2,
                    const float* __restrict__ b2,
                    f32x4* lds_table /* [64*5] stride-5 */)
{
    const int k = lane;
    const f32x4* W2v = (const f32x4*)W2;   // [64][4]

    #pragma unroll
    for (int pi = 0; pi < 4; ++pi) {
        const int p  = wid * 4 + pi;       // 0..63
        const int ts = p >> 3;
        const int tt = p & 7;

        const float mu = 2.0f / 16.0f;
        float var = 0.0f;
        #pragma unroll
        for (int j = 0; j < TIN; ++j) {
            float h = (j == ts || j == (8 + tt)) ? 1.0f : 0.0f;
            float d = h - mu;
            var += d * d;
        }
        var *= (1.0f / 16.0f);
        const float inv = rsqrtf(var + LN_EPS);

        float a = b1[k];
        #pragma unroll
        for (int j = 0; j < TIN; ++j) {
            float h  = (j == ts || j == (8 + tt)) ? 1.0f : 0.0f;
            float hn = (h - mu) * inv * ln_g[j] + ln_b[j];
            a += hn * W1[j * HID + k];
        }
        a = fmaxf(a, 0.0f);

        #pragma unroll
        for (int h = 0; h < 2; ++h) {      // two 8-output passes (low VGPR)
            f32x4 wlo = W2v[k * 4 + 2 * h];
            f32x4 whi = W2v[k * 4 + 2 * h + 1];
            float s[8];
            #pragma unroll
            for (int i = 0; i < 4; ++i) { s[i] = a * wlo[i]; s[4 + i] = a * whi[i]; }
            #pragma unroll
            for (int o = 0; o < 8; ++o) {
                s[o] += __shfl_xor(s[o], 1);
                s[o] += __shfl_xor(s[o], 2);
                s[o] += __shfl_xor(s[o], 4);
                s[o] += __shfl_xor(s[o], 8);
                s[o] += __shfl_xor(s[o], 16);
                s[o] += __shfl_xor(s[o], 32);
                s[o] += b2[8 * h + o];
            }
            if (lane < 2) {                // lane 0 -> row 2h, lane 1 -> row 2h+1
                const int r  = 2 * h + lane;
                const int o0 = 4 * lane;
                float s0 = s[o0+0], s1 = s[o0+1], s2 = s[o0+2], s3 = s[o0+3];
                float m  = fmaxf(fmaxf(s0, s1), fmaxf(s2, s3));
                float e0 = expf(s0 - m), e1 = expf(s1 - m),
                      e2 = expf(s2 - m), e3 = expf(s3 - m);
                float rs = 1.0f / (e0 + e1 + e2 + e3);
                f32x4 outv;
                outv.x = (r == 0 ? 1.0f : 0.0f) - e0 * rs;
                outv.y = (r == 1 ? 1.0f : 0.0f) - e1 * rs;
                outv.z = (r == 2 ? 1.0f : 0.0f) - e2 * rs;
                outv.w = (r == 3 ? 1.0f : 0.0f) - e3 * rs;
                lds_table[p * 5 + r] = outv;
            }
        }
    }
}

// ---------------------------------------------------------------------------
// k1: scatter (R9 structure: 64-edge chunks, 1-deep index prefetch,
// zero hot-loop predication when E%64==0) + in-block table build +
// nontemporal stores (bypass L2: the 205MB write stream otherwise thrashes
// the L2 serving every block's nibble/index reads).
// ---------------------------------------------------------------------------
template <bool EXACT>
__global__ __launch_bounds__(1024) void
scatter_edges_kernel(const int* __restrict__ row,
                     const int* __restrict__ col,
                     const unsigned int* __restrict__ packed, // [N_PACK_U32]
                     const float* __restrict__ ln_g,
                     const float* __restrict__ ln_b,
                     const float* __restrict__ W1,
                     const float* __restrict__ b1,
                     const float* __restrict__ W2,
                     const float* __restrict__ b2,
                     f32x4* __restrict__ out4,                // [E][4]
                     int E)
{
    __shared__ f32x4 lds_table[64 * 5];              // stride-5 pad (bank fix)
    __shared__ unsigned int nt_lds[N_PACK_U32];      // 50 KB packed nibbles

    const int t    = threadIdx.x;
    const int lane = t & 63;
    const int wid  = t >> 6;             // wave in block, 0..15

    {   // stage packed types (50 KB); loads issue first, fill under table build
        const uint4* s4 = (const uint4*)packed;
        uint4* d4 = (uint4*)nt_lds;
        for (int i = t; i < N_PACK_U32 / 4; i += 1024) d4[i] = s4[i];
    }
    // table build overlapped with staging loads (VALU + L2-hot weight reads)
    build_table_inblock(wid, lane, ln_g, ln_b, W1, b1, W2, b2, lds_table);
    __syncthreads();

    const int q    = lane & 3;           // output quad
    const int sub  = lane >> 2;          // 0..15
    const int stride = gridDim.x * 1024; // 16 waves * 64 edges per block

    int base = blockIdx.x * 1024 + wid * 64;
    if (base >= E) return;

    // Prologue: load + pair for the first chunk.
    int pair;
    {
        int e  = base + lane;
        int ec = EXACT ? e : ((e < E) ? e : (E - 1));
        int r = row[ec];
        int c = col[ec];
        unsigned int tr = (nt_lds[r >> 3] >> ((r & 7) * 4)) & 7u;
        unsigned int tc = (nt_lds[c >> 3] >> ((c & 7) * 4)) & 7u;
        pair = (int)((tr << 3) | tc);
    }

    while (base < E) {
        const int nbase = base + stride;
        const bool have_next = (nbase < E);

        // top: prefetch next chunk's indices (hidden under store issuance)
        int rn = 0, cn = 0;
        if (have_next) {
            int en  = nbase + lane;
            int enc = EXACT ? en : ((en < E) ? en : (E - 1));
            rn = row[enc];
            cn = col[enc];
        }

        // middle: four independent coalesced 1 KB wave stores (nontemporal)
        #pragma unroll
        for (int j = 0; j < 4; ++j) {
            int src = j * 16 + sub;
            int pj  = __shfl(pair, src, 64);
            if (EXACT) {
                f32x4 v = lds_table[pj * 5 + q];
                __builtin_nontemporal_store(v, &out4[(base + src) * 4 + q]);
            } else {
                int ej = base + src;
                if (ej < E) {
                    f32x4 v = lds_table[pj * 5 + q];
                    __builtin_nontemporal_store(v, &out4[ej * 4 + q]);
                }
            }
        }

        // bottom: pair for the prefetched chunk
        if (have_next) {
            unsigned int tr = (nt_lds[rn >> 3] >> ((rn & 7) * 4)) & 7u;
            unsigned int tc = (nt_lds[cn >> 3] >> ((cn & 7) * 4)) & 7u;
            pair = (int)((tr << 3) | tc);
        }
        base = nbase;
    }
}

// ---------------------------------------------------------------------------
extern "C" void kernel_launch(void* const* d_in, const int* in_sizes, int n_in,
                              void* d_out, int out_size, void* d_ws, size_t ws_size,
                              hipStream_t stream)
{
    // Inputs: x, edge_index, node_types, ln_g, ln_b, W1, b1, W2, b2
    const int*   edge_index = (const int*)d_in[1];   // [2][E] int32
    const int*   ntypes     = (const int*)d_in[2];   // [N] int32
    const float* ln_g       = (const float*)d_in[3];
    const float* ln_b       = (const float*)d_in[4];
    const float* W1         = (const float*)d_in[5];
    const float* b1         = (const float*)d_in[6];
    const float* W2         = (const float*)d_in[7];
    const float* b2         = (const float*)d_in[8];

    const int E = in_sizes[1] / 2;
    const int N = in_sizes[2];

    unsigned int* packed = (unsigned int*)d_ws;      // 50 KB

    pack_kernel<<<PACK_BLOCKS, 256, 0, stream>>>(ntypes, N, packed);

    const int blocks = 512;   // 2 blocks/CU (55KB LDS)
    if ((E & 63) == 0) {
        scatter_edges_kernel<true><<<blocks, 1024, 0, stream>>>(
            edge_index, edge_index + E, packed,
            ln_g, ln_b, W1, b1, W2, b2, (f32x4*)d_out, E);
    } else {
        scatter_edges_kernel<false><<<blocks, 1024, 0, stream>>>(
            edge_index, edge_index + E, packed,
            ln_g, ln_b, W1, b1, W2, b2, (f32x4*)d_out, E);
    }
}

// Round 12
// 46.008 us; speedup vs baseline: 1.7893x; 1.7893x over previous
//
#include <hip/hip_runtime.h>
#include <math.h>

// Problem constants (from reference)
#define NUM_T   8      // NUM_NODE_TYPES
#define TIN     16     // 2 * NUM_NODE_TYPES
#define HID     64     // HIDDEN
#define OUTD    16     // D*D
#define LN_EPS  1e-5f

#define N_PACK_U32  12500   // ceil(100000 / 8) ; 12500 % 4 == 0
#define PACK_BLOCKS 49      // ceil(12500 / 256)

typedef float f32x4 __attribute__((ext_vector_type(4)));

// ---------------------------------------------------------------------------
// k0: blocks [0,49): pack node types to nibbles (8 per u32).
//     blocks [49,113): one (ts,tt) pair per block; one wave computes the
//     16-float output row straight from L2 (coalesced, no LDS).
// ws: [0,4KB) table ; [4KB,54KB) packed nibbles.
// NOTE (R11 lesson): building this table per-scatter-block costs ~27us of
// VALU serialization across resident waves — build it ONCE here.
// ---------------------------------------------------------------------------
__global__ __launch_bounds__(256) void
prep_kernel(const int* __restrict__ ntypes, int n_nodes,
            const float* __restrict__ ln_g,
            const float* __restrict__ ln_b,
            const float* __restrict__ W1,   // [16][64]
            const float* __restrict__ b1,   // [64]
            const float* __restrict__ W2,   // [64][16]
            const float* __restrict__ b2,   // [16]
            f32x4* __restrict__ table4,     // [64][4]
            unsigned int* __restrict__ packed)
{
    const int t = threadIdx.x;

    if (blockIdx.x < PACK_BLOCKS) {
        const int g = blockIdx.x * 256 + t;
        if (g < N_PACK_U32) {
            unsigned int w = 0;
            int n0 = g * 8;
            #pragma unroll
            for (int j = 0; j < 8; ++j) {
                int n = n0 + j;
                unsigned int ty = (n < n_nodes) ? (unsigned int)ntypes[n] : 0u;
                w |= (ty & 7u) << (j * 4);
            }
            packed[g] = w;
        }
        return;
    }

    // ---- table build: one pair per block, lanes 0..63 = k ----
    if (t >= 64) return;
    const int p  = blockIdx.x - PACK_BLOCKS;   // 0..63
    const int ts = p >> 3;
    const int tt = p & 7;
    const int k  = t;

    const float mu = 2.0f / 16.0f;
    float var = 0.0f;
    #pragma unroll
    for (int j = 0; j < TIN; ++j) {
        float h = (j == ts || j == (8 + tt)) ? 1.0f : 0.0f;
        float d = h - mu;
        var += d * d;
    }
    var *= (1.0f / 16.0f);
    const float inv = rsqrtf(var + LN_EPS);

    float a = b1[k];
    #pragma unroll
    for (int j = 0; j < TIN; ++j) {
        float h  = (j == ts || j == (8 + tt)) ? 1.0f : 0.0f;
        float hn = (h - mu) * inv * ln_g[j] + ln_b[j];
        a += hn * W1[j * HID + k];
    }
    a = fmaxf(a, 0.0f);

    const f32x4* W2v = (const f32x4*)W2;   // [64][4]
    f32x4 w0 = W2v[k * 4 + 0], w1 = W2v[k * 4 + 1],
          w2 = W2v[k * 4 + 2], w3 = W2v[k * 4 + 3];

    float s[OUTD];
    #pragma unroll
    for (int i = 0; i < 4; ++i) {
        s[0 + i]  = a * w0[i];
        s[4 + i]  = a * w1[i];
        s[8 + i]  = a * w2[i];
        s[12 + i] = a * w3[i];
    }
    #pragma unroll
    for (int o = 0; o < OUTD; ++o) {
        s[o] += __shfl_xor(s[o], 1);
        s[o] += __shfl_xor(s[o], 2);
        s[o] += __shfl_xor(s[o], 4);
        s[o] += __shfl_xor(s[o], 8);
        s[o] += __shfl_xor(s[o], 16);
        s[o] += __shfl_xor(s[o], 32);
        s[o] += b2[o];
    }

    if (t < 4) {
        const int r = t;
        float s0 = s[4*r+0], s1 = s[4*r+1], s2 = s[4*r+2], s3 = s[4*r+3];
        float m  = fmaxf(fmaxf(s0, s1), fmaxf(s2, s3));
        float e0 = expf(s0 - m), e1 = expf(s1 - m),
              e2 = expf(s2 - m), e3 = expf(s3 - m);
        float rs = 1.0f / (e0 + e1 + e2 + e3);
        f32x4 outv;
        outv.x = (r == 0 ? 1.0f : 0.0f) - e0 * rs;
        outv.y = (r == 1 ? 1.0f : 0.0f) - e1 * rs;
        outv.z = (r == 2 ? 1.0f : 0.0f) - e2 * rs;
        outv.w = (r == 3 ? 1.0f : 0.0f) - e3 * rs;
        table4[p * 4 + r] = outv;
    }
}

// ---------------------------------------------------------------------------
// k1: scatter, 1024-thread blocks, 2 blocks/CU (55 KB LDS) = 32 waves/CU.
// 1-deep software pipeline (prefetch next chunk's indices before stores).
// EXACT=true (E % 64 == 0): zero predication in the hot loop.
// Plain stores (nt regressed in combination testing; fills show plain
// stores reach 6.9 TB/s).
// ---------------------------------------------------------------------------
template <bool EXACT>
__global__ __launch_bounds__(1024) void
scatter_edges_kernel(const int* __restrict__ row,
                     const int* __restrict__ col,
                     const unsigned int* __restrict__ packed, // [N_PACK_U32]
                     const f32x4* __restrict__ table4,        // [64][4]
                     f32x4* __restrict__ out4,                // [E][4]
                     int E)
{
    __shared__ f32x4 lds_table[64 * 5];              // stride-5 pad (bank fix)
    __shared__ unsigned int nt_lds[N_PACK_U32];      // 50 KB packed nibbles

    const int t = threadIdx.x;

    if (t < 256) {   // stage table (5 KB)
        int p = t >> 2, q = t & 3;
        lds_table[p * 5 + q] = table4[t];
    }
    {   // stage packed types (50 KB); 12500/4 = 3125 exact
        const uint4* s4 = (const uint4*)packed;
        uint4* d4 = (uint4*)nt_lds;
        for (int i = t; i < N_PACK_U32 / 4; i += 1024) d4[i] = s4[i];
    }
    __syncthreads();

    const int lane = t & 63;
    const int wid  = t >> 6;             // wave in block, 0..15
    const int q    = lane & 3;           // output quad
    const int sub  = lane >> 2;          // 0..15
    const int stride = gridDim.x * 1024; // 16 waves * 64 edges per block

    int base = blockIdx.x * 1024 + wid * 64;
    if (base >= E) return;

    // Prologue: load + pair for the first chunk.
    int pair;
    {
        int e  = base + lane;
        int ec = EXACT ? e : ((e < E) ? e : (E - 1));
        int r = row[ec];
        int c = col[ec];
        unsigned int tr = (nt_lds[r >> 3] >> ((r & 7) * 4)) & 7u;
        unsigned int tc = (nt_lds[c >> 3] >> ((c & 7) * 4)) & 7u;
        pair = (int)((tr << 3) | tc);
    }

    while (base < E) {
        const int nbase = base + stride;
        const bool have_next = (nbase < E);

        // top: prefetch next chunk's indices (hidden under store issuance)
        int rn = 0, cn = 0;
        if (have_next) {
            int en  = nbase + lane;
            int enc = EXACT ? en : ((en < E) ? en : (E - 1));
            rn = row[enc];
            cn = col[enc];
        }

        // middle: four independent coalesced 1 KB wave stores
        #pragma unroll
        for (int j = 0; j < 4; ++j) {
            int src = j * 16 + sub;
            int pj  = __shfl(pair, src, 64);
            if (EXACT) {
                out4[(base + src) * 4 + q] = lds_table[pj * 5 + q];
            } else {
                int ej = base + src;
                if (ej < E) out4[ej * 4 + q] = lds_table[pj * 5 + q];
            }
        }

        // bottom: pair for the prefetched chunk
        if (have_next) {
            unsigned int tr = (nt_lds[rn >> 3] >> ((rn & 7) * 4)) & 7u;
            unsigned int tc = (nt_lds[cn >> 3] >> ((cn & 7) * 4)) & 7u;
            pair = (int)((tr << 3) | tc);
        }
        base = nbase;
    }
}

// ---------------------------------------------------------------------------
extern "C" void kernel_launch(void* const* d_in, const int* in_sizes, int n_in,
                              void* d_out, int out_size, void* d_ws, size_t ws_size,
                              hipStream_t stream)
{
    // Inputs: x, edge_index, node_types, ln_g, ln_b, W1, b1, W2, b2
    const int*   edge_index = (const int*)d_in[1];   // [2][E] int32
    const int*   ntypes     = (const int*)d_in[2];   // [N] int32
    const float* ln_g       = (const float*)d_in[3];
    const float* ln_b       = (const float*)d_in[4];
    const float* W1         = (const float*)d_in[5];
    const float* b1         = (const float*)d_in[6];
    const float* W2         = (const float*)d_in[7];
    const float* b2         = (const float*)d_in[8];

    const int E = in_sizes[1] / 2;
    const int N = in_sizes[2];

    f32x4*        table4 = (f32x4*)d_ws;                        // 4 KB
    unsigned int* packed = (unsigned int*)((char*)d_ws + 4096); // 50 KB

    prep_kernel<<<PACK_BLOCKS + 64, 256, 0, stream>>>(
        ntypes, N, ln_g, ln_b, W1, b1, W2, b2, table4, packed);

    const int blocks = 512;   // 2 blocks/CU (55KB LDS), 32 waves/CU
    if ((E & 63) == 0) {
        scatter_edges_kernel<true><<<blocks, 1024, 0, stream>>>(
            edge_index, edge_index + E, packed, table4, (f32x4*)d_out, E);
    } else {
        scatter_edges_kernel<false><<<blocks, 1024, 0, stream>>>(
            edge_index, edge_index + E, packed, table4, (f32x4*)d_out, E);
    }
}